// Round 1
// baseline (1472.966 us; speedup 1.0000x reference)
//
#include <hip/hip_runtime.h>

#define INF 256
#define HF 128
#define POOL_SPLIT 8

// ---- roots[g] = first node of graph g (batch sorted, all graphs non-empty) ----
__global__ void k_roots(const int* __restrict__ batch, int* __restrict__ roots, int N, int B) {
    int i = blockIdx.x * blockDim.x + threadIdx.x;
    if (i == 0) roots[B] = N;
    if (i < N) {
        if (i == 0) roots[batch[0]] = 0;
        else if (batch[i] != batch[i - 1]) roots[batch[i]] = i;
    }
}

__global__ void k_deg_init(float* __restrict__ deg, int nv) {
    int i = blockIdx.x * blockDim.x + threadIdx.x;
    if (i < nv) deg[i] = 1.0f;  // self-loop
}

// deg over the "d" side. flip=0: d=dst (TD). flip=1: d=src (BU).
__global__ void k_deg_edges(const int* __restrict__ src, const int* __restrict__ dst,
                            const int* __restrict__ roots, float* __restrict__ deg,
                            int E, int B, int N, int flip) {
    int e = blockIdx.x * blockDim.x + threadIdx.x;
    if (e >= E + B) return;
    int a, b;
    if (e < E) { a = src[e]; b = dst[e]; }
    else       { a = N;      b = roots[e - E]; }   // virtual edge n -> root
    int d = flip ? a : b;
    atomicAdd(&deg[d], 1.0f);
}

__global__ void k_dinv(float* __restrict__ deg, int nv) {
    int i = blockIdx.x * blockDim.x + threadIdx.x;
    if (i < nv) deg[i] = rsqrtf(deg[i]);
}

// GEMM1: raw[v][t] = sum_k xv[v][k] * W[k][t], W: 256x128 row-major
__global__ __launch_bounds__(128) void k_gemm1(const float* __restrict__ x, const float* __restrict__ emb,
                                               const float* __restrict__ W, float* __restrict__ raw, int N) {
    __shared__ float row[INF];
    int v = blockIdx.x;
    const float* xr = (v < N) ? (x + (size_t)v * INF) : emb;
    int t = threadIdx.x;
    row[t]       = xr[t];
    row[t + 128] = xr[t + 128];
    __syncthreads();
    float acc = 0.f;
    #pragma unroll 8
    for (int k = 0; k < INF; ++k)
        acc = fmaf(row[k], W[k * HF + t], acc);
    raw[(size_t)v * HF + t] = acc;
}

// GEMM2: raw[v][t] = sum_k relu(accin[v][k]) * W[k][t], W: 128x128 row-major
__global__ __launch_bounds__(128) void k_gemm2(const float* __restrict__ accin,
                                               const float* __restrict__ W, float* __restrict__ raw, int nv) {
    __shared__ float row[HF];
    int v = blockIdx.x;
    int t = threadIdx.x;
    float xv = accin[(size_t)v * HF + t];
    row[t] = xv > 0.f ? xv : 0.f;
    __syncthreads();
    float acc = 0.f;
    #pragma unroll 8
    for (int k = 0; k < HF; ++k)
        acc = fmaf(row[k], W[k * HF + t], acc);
    raw[(size_t)v * HF + t] = acc;
}

// acc[v][t] = raw[v][t] * dinv[v]^2 (self-loop) + bias[t]
__global__ void k_selfinit(const float* __restrict__ raw, const float* __restrict__ dinv,
                           const float* __restrict__ bias, float* __restrict__ acc, int nv) {
    size_t i = (size_t)blockIdx.x * blockDim.x + threadIdx.x;
    if (i < (size_t)nv * HF) {
        int v = (int)(i >> 7);
        int t = (int)(i & 127);
        float di = dinv[v];
        acc[i] = raw[i] * di * di + bias[t];
    }
}

// acc[d] += raw[s] * dinv[s] * dinv[d]
__global__ __launch_bounds__(128) void k_scatter(const int* __restrict__ src, const int* __restrict__ dst,
                                                 const int* __restrict__ roots,
                                                 const float* __restrict__ raw, const float* __restrict__ dinv,
                                                 float* __restrict__ acc, int E, int B, int N, int flip) {
    int e = blockIdx.x;
    int a, b;
    if (e < E) { a = src[e]; b = dst[e]; }
    else       { a = N;      b = roots[e - E]; }
    int s = flip ? b : a;
    int d = flip ? a : b;
    float nrm = dinv[s] * dinv[d];
    int t = threadIdx.x;
    atomicAdd(&acc[(size_t)d * HF + t], raw[(size_t)s * HF + t] * nrm);
}

__global__ void k_zero(float* __restrict__ p, int n) {
    int i = blockIdx.x * blockDim.x + threadIdx.x;
    if (i < n) p[i] = 0.f;
}

// pooled[g][t] = sum_{i in graph g} acc[i][t]  (+ virtual row once, via part 0)
__global__ __launch_bounds__(128) void k_pool(const float* __restrict__ acc, const int* __restrict__ roots,
                                              float* __restrict__ pooled, int N) {
    int g = blockIdx.x / POOL_SPLIT;
    int part = blockIdx.x % POOL_SPLIT;
    int s = roots[g], e = roots[g + 1];
    int len = e - s;
    int chunk = (len + POOL_SPLIT - 1) / POOL_SPLIT;
    int lo = s + part * chunk;
    int hi = min(lo + chunk, e);
    int t = threadIdx.x;
    float sum = 0.f;
    if (part == 0) sum = acc[(size_t)N * HF + t];  // virtual node row
    for (int i = lo; i < hi; ++i) sum += acc[(size_t)i * HF + t];
    if (part == 0 || lo < hi) atomicAdd(&pooled[g * HF + t], sum);
}

// out = relu([bu, td] @ w1 + b1) @ w2 + b2
__global__ __launch_bounds__(256) void k_mlp(const float* __restrict__ p_bu, const float* __restrict__ p_td,
                                             const float* __restrict__ w1, const float* __restrict__ b1,
                                             const float* __restrict__ w2, const float* __restrict__ b2,
                                             float* __restrict__ out) {
    __shared__ float invec[256];
    __shared__ float hid[256];
    int g = blockIdx.x;
    int t = threadIdx.x;
    invec[t] = (t < 128) ? p_bu[g * 128 + t] : p_td[g * 128 + (t - 128)];
    __syncthreads();
    float acc = b1[t];
    #pragma unroll 8
    for (int k = 0; k < 256; ++k) acc = fmaf(invec[k], w1[k * 256 + t], acc);
    hid[t] = acc > 0.f ? acc : 0.f;
    __syncthreads();
    if (t < 128) {
        float o = b2[t];
        #pragma unroll 8
        for (int k = 0; k < 256; ++k) o = fmaf(hid[k], w2[k * 128 + t], o);
        out[g * 128 + t] = o;
    }
}

extern "C" void kernel_launch(void* const* d_in, const int* in_sizes, int n_in,
                              void* d_out, int out_size, void* d_ws, size_t ws_size,
                              hipStream_t stream) {
    const float* x     = (const float*)d_in[0];
    const float* emb_w = (const float*)d_in[1];
    const float* td_w1 = (const float*)d_in[2];
    const float* td_b1 = (const float*)d_in[3];
    const float* td_w2 = (const float*)d_in[4];
    const float* td_b2 = (const float*)d_in[5];
    const float* bu_w1 = (const float*)d_in[6];
    const float* bu_b1 = (const float*)d_in[7];
    const float* bu_w2 = (const float*)d_in[8];
    const float* bu_b2 = (const float*)d_in[9];
    const float* p_w1  = (const float*)d_in[10];
    const float* p_b1  = (const float*)d_in[11];
    const float* p_w2  = (const float*)d_in[12];
    const float* p_b2  = (const float*)d_in[13];
    const int*   ei    = (const int*)d_in[14];
    const int*   batch = (const int*)d_in[15];

    int N = in_sizes[0] / INF;
    int E = in_sizes[14] / 2;
    int B = out_size / 128;
    int nv = N + 1;
    const int* src = ei;
    const int* dst = ei + E;

    float* ws = (float*)d_ws;
    size_t nvf = (size_t)nv * HF;
    float* RAW  = ws;  ws += nvf;
    float* ACC  = ws;  ws += nvf;
    float* dinv = ws;  ws += nv;
    float* p_td = ws;  ws += (size_t)B * HF;
    float* p_bu = ws;  ws += (size_t)B * HF;
    int*   roots = (int*)ws;  // B+1 ints

    float* out = (float*)d_out;

    dim3 b256(256), b128(128);
    k_roots<<<dim3((N + 255) / 256), b256, 0, stream>>>(batch, roots, N, B);
    // p_td and p_bu are contiguous: zero both in one shot
    k_zero<<<dim3((2 * B * HF + 255) / 256), b256, 0, stream>>>(p_td, 2 * B * HF);

    for (int branch = 0; branch < 2; ++branch) {
        int flip = branch;  // 0 = TD (s=src,d=dst), 1 = BU (flipped)
        const float* w1 = flip ? bu_w1 : td_w1;
        const float* b1 = flip ? bu_b1 : td_b1;
        const float* w2 = flip ? bu_w2 : td_w2;
        const float* b2 = flip ? bu_b2 : td_b2;
        float* pooled   = flip ? p_bu : p_td;

        k_deg_init<<<dim3((nv + 255) / 256), b256, 0, stream>>>(dinv, nv);
        k_deg_edges<<<dim3((E + B + 255) / 256), b256, 0, stream>>>(src, dst, roots, dinv, E, B, N, flip);
        k_dinv<<<dim3((nv + 255) / 256), b256, 0, stream>>>(dinv, nv);

        k_gemm1<<<dim3(nv), b128, 0, stream>>>(x, emb_w, w1, RAW, N);
        k_selfinit<<<dim3((unsigned)((nvf + 255) / 256)), b256, 0, stream>>>(RAW, dinv, b1, ACC, nv);
        k_scatter<<<dim3(E + B), b128, 0, stream>>>(src, dst, roots, RAW, dinv, ACC, E, B, N, flip);

        k_gemm2<<<dim3(nv), b128, 0, stream>>>(ACC, w2, RAW, nv);
        k_selfinit<<<dim3((unsigned)((nvf + 255) / 256)), b256, 0, stream>>>(RAW, dinv, b2, ACC, nv);
        k_scatter<<<dim3(E + B), b128, 0, stream>>>(src, dst, roots, RAW, dinv, ACC, E, B, N, flip);

        k_pool<<<dim3(B * POOL_SPLIT), b128, 0, stream>>>(ACC, roots, pooled, N);
    }

    k_mlp<<<dim3(B), b256, 0, stream>>>(p_bu, p_td, p_w1, p_b1, p_w2, p_b2, out);
}

// Round 2
// 459.324 us; speedup vs baseline: 3.2068x; 3.2068x over previous
//
#include <hip/hip_runtime.h>

typedef __bf16 bf16_t;
typedef __bf16 bf16x8 __attribute__((ext_vector_type(8)));
typedef __bf16 bf16x4 __attribute__((ext_vector_type(4)));
typedef float f32x4 __attribute__((ext_vector_type(4)));

#define INF 256
#define HF 128
#define POOL_SPLIT 8

// ---- roots[g] = first node of graph g (batch sorted, all graphs non-empty) ----
__global__ void k_roots(const int* __restrict__ batch, int* __restrict__ roots, int N, int B) {
    int i = blockIdx.x * blockDim.x + threadIdx.x;
    if (i == 0) roots[B] = N;
    if (i < N) {
        if (i == 0) roots[batch[0]] = 0;
        else if (batch[i] != batch[i - 1]) roots[batch[i]] = i;
    }
}

__global__ void k_deg_init(float* __restrict__ deg, int nv) {
    int i = blockIdx.x * blockDim.x + threadIdx.x;
    if (i < nv) deg[i] = 1.0f;  // self-loop
}

__global__ void k_deg_edges(const int* __restrict__ src, const int* __restrict__ dst,
                            const int* __restrict__ roots, float* __restrict__ deg,
                            int E, int B, int N, int flip) {
    int e = blockIdx.x * blockDim.x + threadIdx.x;
    if (e >= E + B) return;
    int a, b;
    if (e < E) { a = src[e]; b = dst[e]; }
    else       { a = N;      b = roots[e - E]; }   // virtual edge n -> root
    int d = flip ? a : b;
    atomicAdd(&deg[d], 1.0f);
}

__global__ void k_dinv(float* __restrict__ deg, int nv) {
    int i = blockIdx.x * blockDim.x + threadIdx.x;
    if (i < nv) deg[i] = rsqrtf(deg[i]);
}

__global__ void k_zero(float* __restrict__ p, int n) {
    int i = blockIdx.x * blockDim.x + threadIdx.x;
    if (i < n) p[i] = 0.f;
}

// Pre-swizzle W[K][128] f32 -> bf16 in exact B-fragment order:
// out[((kk*8+n)*64+l)*8+j] = W[kk*32+(l>>4)*8+j][n*16+(l&15)]
__global__ void k_wswz(const float* __restrict__ W, bf16_t* __restrict__ out, int K) {
    int idx = blockIdx.x * blockDim.x + threadIdx.x;
    if (idx >= K * 128) return;
    int j  = idx & 7;
    int l  = (idx >> 3) & 63;
    int t  = idx >> 9;        // kk*8 + n
    int n  = t & 7;
    int kk = t >> 3;
    int k  = kk * 32 + (l >> 4) * 8 + j;
    int c  = n * 16 + (l & 15);
    out[idx] = (bf16_t)W[k * 128 + c];
}

// MFMA GEMM: out rows [0,nv) x 128 cols. A = f32 X (+emb row N) if AF32, else bf16 Ab.
// Epilogue fuses self-loop + bias:
//   raws[r][c] = (raw * dinv[r])          (bf16)
//   acc [r][c] = raw * dinv[r]^2 + bias[c]
template<int K, bool AF32>
__global__ __launch_bounds__(256) void k_gemm_mfma(
    const float* __restrict__ Af, const bf16_t* __restrict__ Ab,
    const float* __restrict__ emb,
    const bf16_t* __restrict__ Wf,
    const float* __restrict__ dinv, const float* __restrict__ bias,
    bf16_t* __restrict__ raws, float* __restrict__ accout,
    int nv, int N)
{
    constexpr int NK = K / 32;
    int lane = threadIdx.x & 63;
    int wave = threadIdx.x >> 6;
    int rowbase = blockIdx.x * 64 + wave * 16;
    int r = rowbase + (lane & 15);      // A row this lane loads
    int kseg = lane >> 4;

    f32x4 acc[8] = {};

    #pragma unroll
    for (int kk = 0; kk < NK; ++kk) {
        int k0 = kk * 32 + kseg * 8;
        bf16x8 a;
        if constexpr (AF32) {
            const float* xr = nullptr;
            if (r < N) xr = Af + (size_t)r * K;
            else if (r == N) xr = emb;
            if (xr) {
                float4 v0 = *reinterpret_cast<const float4*>(xr + k0);
                float4 v1 = *reinterpret_cast<const float4*>(xr + k0 + 4);
                a[0] = (__bf16)v0.x; a[1] = (__bf16)v0.y; a[2] = (__bf16)v0.z; a[3] = (__bf16)v0.w;
                a[4] = (__bf16)v1.x; a[5] = (__bf16)v1.y; a[6] = (__bf16)v1.z; a[7] = (__bf16)v1.w;
            } else {
                #pragma unroll
                for (int j = 0; j < 8; ++j) a[j] = (__bf16)0.0f;
            }
        } else {
            if (r < nv) {
                a = *reinterpret_cast<const bf16x8*>(Ab + (size_t)r * K + k0);
            } else {
                #pragma unroll
                for (int j = 0; j < 8; ++j) a[j] = (__bf16)0.0f;
            }
        }
        #pragma unroll
        for (int n = 0; n < 8; ++n) {
            bf16x8 b = *reinterpret_cast<const bf16x8*>(Wf + (size_t)(((kk << 3) + n) * 64 + lane) * 8);
            acc[n] = __builtin_amdgcn_mfma_f32_16x16x32_bf16(a, b, acc[n], 0, 0, 0);
        }
    }

    // epilogue: C/D layout col=lane&15, row=(lane>>4)*4+i  [m89-verified]
    int ccol = lane & 15;
    int cg = lane >> 4;
    #pragma unroll
    for (int i = 0; i < 4; ++i) {
        int rr = rowbase + cg * 4 + i;
        if (rr >= nv) continue;
        float di = dinv[rr];
        #pragma unroll
        for (int n = 0; n < 8; ++n) {
            int col = n * 16 + ccol;
            float v = acc[n][i];
            float rs = v * di;
            raws[(size_t)rr * HF + col] = (bf16_t)rs;
            accout[(size_t)rr * HF + col] = fmaf(rs, di, bias[col]);
        }
    }
}

// acc[d] += raws[s] * dinv[d]   (dinv[s] already folded into raws)
__global__ __launch_bounds__(128) void k_scatter(const int* __restrict__ src, const int* __restrict__ dst,
                                                 const int* __restrict__ roots,
                                                 const bf16_t* __restrict__ raws, const float* __restrict__ dinv,
                                                 float* __restrict__ acc, int E, int B, int N, int flip) {
    int e = blockIdx.x;
    int a, b;
    if (e < E) { a = src[e]; b = dst[e]; }
    else       { a = N;      b = roots[e - E]; }
    int s = flip ? b : a;
    int d = flip ? a : b;
    float nd = dinv[d];
    int t = threadIdx.x;
    float v = (float)raws[(size_t)s * HF + t];
    atomicAdd(&acc[(size_t)d * HF + t], v * nd);
}

// ab = bf16(relu(acc)), 4 elems/thread
__global__ void k_relucvt(const float* __restrict__ accin, bf16_t* __restrict__ ab, int n4) {
    int i = blockIdx.x * blockDim.x + threadIdx.x;
    if (i < n4) {
        float4 v = reinterpret_cast<const float4*>(accin)[i];
        bf16x4 o;
        o[0] = (__bf16)fmaxf(v.x, 0.f);
        o[1] = (__bf16)fmaxf(v.y, 0.f);
        o[2] = (__bf16)fmaxf(v.z, 0.f);
        o[3] = (__bf16)fmaxf(v.w, 0.f);
        reinterpret_cast<bf16x4*>(ab)[i] = o;
    }
}

// pooled[g][t] = sum_{i in graph g} acc[i][t]  (+ virtual row once, via part 0)
__global__ __launch_bounds__(128) void k_pool(const float* __restrict__ acc, const int* __restrict__ roots,
                                              float* __restrict__ pooled, int N) {
    int g = blockIdx.x / POOL_SPLIT;
    int part = blockIdx.x % POOL_SPLIT;
    int s = roots[g], e = roots[g + 1];
    int len = e - s;
    int chunk = (len + POOL_SPLIT - 1) / POOL_SPLIT;
    int lo = s + part * chunk;
    int hi = min(lo + chunk, e);
    int t = threadIdx.x;
    float sum = 0.f;
    if (part == 0) sum = acc[(size_t)N * HF + t];  // virtual node row
    for (int i = lo; i < hi; ++i) sum += acc[(size_t)i * HF + t];
    if (part == 0 || lo < hi) atomicAdd(&pooled[g * HF + t], sum);
}

// out = relu([bu, td] @ w1 + b1) @ w2 + b2
__global__ __launch_bounds__(256) void k_mlp(const float* __restrict__ p_bu, const float* __restrict__ p_td,
                                             const float* __restrict__ w1, const float* __restrict__ b1,
                                             const float* __restrict__ w2, const float* __restrict__ b2,
                                             float* __restrict__ out) {
    __shared__ float invec[256];
    __shared__ float hid[256];
    int g = blockIdx.x;
    int t = threadIdx.x;
    invec[t] = (t < 128) ? p_bu[g * 128 + t] : p_td[g * 128 + (t - 128)];
    __syncthreads();
    float acc = b1[t];
    #pragma unroll 8
    for (int k = 0; k < 256; ++k) acc = fmaf(invec[k], w1[k * 256 + t], acc);
    hid[t] = acc > 0.f ? acc : 0.f;
    __syncthreads();
    if (t < 128) {
        float o = b2[t];
        #pragma unroll 8
        for (int k = 0; k < 256; ++k) o = fmaf(hid[k], w2[k * 128 + t], o);
        out[g * 128 + t] = o;
    }
}

extern "C" void kernel_launch(void* const* d_in, const int* in_sizes, int n_in,
                              void* d_out, int out_size, void* d_ws, size_t ws_size,
                              hipStream_t stream) {
    const float* x     = (const float*)d_in[0];
    const float* emb_w = (const float*)d_in[1];
    const float* td_w1 = (const float*)d_in[2];
    const float* td_b1 = (const float*)d_in[3];
    const float* td_w2 = (const float*)d_in[4];
    const float* td_b2 = (const float*)d_in[5];
    const float* bu_w1 = (const float*)d_in[6];
    const float* bu_b1 = (const float*)d_in[7];
    const float* bu_w2 = (const float*)d_in[8];
    const float* bu_b2 = (const float*)d_in[9];
    const float* p_w1  = (const float*)d_in[10];
    const float* p_b1  = (const float*)d_in[11];
    const float* p_w2  = (const float*)d_in[12];
    const float* p_b2  = (const float*)d_in[13];
    const int*   ei    = (const int*)d_in[14];
    const int*   batch = (const int*)d_in[15];

    int N = in_sizes[0] / INF;
    int E = in_sizes[14] / 2;
    int B = out_size / 128;
    int nv = N + 1;
    const int* src = ei;
    const int* dst = ei + E;

    // ---- workspace carve-up (256B-aligned segments), ~78 MB total ----
    char* wsp = (char*)d_ws;
    auto alloc = [&](size_t bytes) { char* p = wsp; wsp += (bytes + 255) & ~(size_t)255; return p; };
    float*  ACC    = (float*) alloc((size_t)nv * HF * 4);
    bf16_t* RAWS   = (bf16_t*)alloc((size_t)nv * HF * 2);
    float*  dinv   = (float*) alloc((size_t)nv * 4);
    float*  pooled = (float*) alloc((size_t)2 * B * HF * 4);
    int*    roots  = (int*)   alloc((size_t)(B + 1) * 4);
    bf16_t* w1f_td = (bf16_t*)alloc((size_t)INF * HF * 2);
    bf16_t* w2f_td = (bf16_t*)alloc((size_t)HF * HF * 2);
    bf16_t* w1f_bu = (bf16_t*)alloc((size_t)INF * HF * 2);
    bf16_t* w2f_bu = (bf16_t*)alloc((size_t)HF * HF * 2);
    float* p_td = pooled;
    float* p_bu = pooled + (size_t)B * HF;

    float* out = (float*)d_out;

    dim3 b256(256), b128(128);
    k_roots<<<dim3((N + 255) / 256), b256, 0, stream>>>(batch, roots, N, B);
    k_zero<<<dim3((2 * B * HF + 255) / 256), b256, 0, stream>>>(pooled, 2 * B * HF);
    k_wswz<<<dim3((INF * HF + 255) / 256), b256, 0, stream>>>(td_w1, w1f_td, INF);
    k_wswz<<<dim3((HF * HF + 255) / 256), b256, 0, stream>>>(td_w2, w2f_td, HF);
    k_wswz<<<dim3((INF * HF + 255) / 256), b256, 0, stream>>>(bu_w1, w1f_bu, INF);
    k_wswz<<<dim3((HF * HF + 255) / 256), b256, 0, stream>>>(bu_w2, w2f_bu, HF);

    int nvb = (nv + 63) / 64;
    int n4 = nv * HF / 4;

    for (int branch = 0; branch < 2; ++branch) {
        int flip = branch;  // 0 = TD (s=src,d=dst), 1 = BU (flipped)
        const bf16_t* w1f = flip ? w1f_bu : w1f_td;
        const float*  b1  = flip ? bu_b1 : td_b1;
        const bf16_t* w2f = flip ? w2f_bu : w2f_td;
        const float*  b2  = flip ? bu_b2 : td_b2;
        float* pb         = flip ? p_bu : p_td;

        k_deg_init<<<dim3((nv + 255) / 256), b256, 0, stream>>>(dinv, nv);
        k_deg_edges<<<dim3((E + B + 255) / 256), b256, 0, stream>>>(src, dst, roots, dinv, E, B, N, flip);
        k_dinv<<<dim3((nv + 255) / 256), b256, 0, stream>>>(dinv, nv);

        k_gemm_mfma<INF, true><<<dim3(nvb), b256, 0, stream>>>(
            x, nullptr, emb_w, w1f, dinv, b1, RAWS, ACC, nv, N);
        k_scatter<<<dim3(E + B), b128, 0, stream>>>(src, dst, roots, RAWS, dinv, ACC, E, B, N, flip);

        k_relucvt<<<dim3((n4 + 255) / 256), b256, 0, stream>>>(ACC, RAWS, n4);
        k_gemm_mfma<HF, false><<<dim3(nvb), b256, 0, stream>>>(
            nullptr, RAWS, nullptr, w2f, dinv, b2, RAWS, ACC, nv, N);
        k_scatter<<<dim3(E + B), b128, 0, stream>>>(src, dst, roots, RAWS, dinv, ACC, E, B, N, flip);

        k_pool<<<dim3(B * POOL_SPLIT), b128, 0, stream>>>(ACC, roots, pb, N);
    }

    k_mlp<<<dim3(B), b256, 0, stream>>>(p_bu, p_td, p_w1, p_b1, p_w2, p_b2, out);
}

// Round 3
// 361.268 us; speedup vs baseline: 4.0772x; 1.2714x over previous
//
#include <hip/hip_runtime.h>

typedef __bf16 bf16_t;
typedef __bf16 bf16x8 __attribute__((ext_vector_type(8)));
typedef __bf16 bf16x4 __attribute__((ext_vector_type(4)));
typedef float f32x4 __attribute__((ext_vector_type(4)));

#define INF 256
#define HF 128

// ---- roots[g] = first node of graph g (batch sorted, all graphs non-empty) ----
__global__ void k_roots(const int* __restrict__ batch, int* __restrict__ roots, int N, int B) {
    int i = blockIdx.x * blockDim.x + threadIdx.x;
    if (i == 0) roots[B] = N;
    if (i < N) {
        if (i == 0) roots[batch[0]] = 0;
        else if (batch[i] != batch[i - 1]) roots[batch[i]] = i;
    }
}

__global__ void k_zero(int* __restrict__ p, int n) {
    int i = blockIdx.x * blockDim.x + threadIdx.x;
    if (i < n) p[i] = 0;
}

// 4 weight matrices -> bf16 in exact MFMA B-fragment order.
// seg layout in o: [td_w1 32768][td_w2 16384][bu_w1 32768][bu_w2 16384]
__global__ void k_wswz4(const float* __restrict__ tw1, const float* __restrict__ tw2,
                        const float* __restrict__ bw1, const float* __restrict__ bw2,
                        bf16_t* __restrict__ o) {
    int idx = blockIdx.x * blockDim.x + threadIdx.x;
    const float* W; bf16_t* out; int i = idx;
    if (i < 32768)      { W = tw1; out = o; }
    else if (i < 49152) { W = tw2; out = o + 32768; i -= 32768; }
    else if (i < 81920) { W = bw1; out = o + 49152; i -= 49152; }
    else if (i < 98304) { W = bw2; out = o + 81920; i -= 81920; }
    else return;
    int j  = i & 7;
    int l  = (i >> 3) & 63;
    int t  = i >> 9;          // kk*8 + n
    int n  = t & 7;
    int kk = t >> 3;
    int k  = kk * 32 + ((l >> 4) << 3) + j;
    int c  = (n << 4) + (l & 15);
    out[i] = (bf16_t)W[k * HF + c];
}

// XB[v][k] = bf16(x[v][k]) for v<N, emb row at v==N. One float4 per thread.
__global__ void k_xcvt(const float* __restrict__ x, const float* __restrict__ emb,
                       bf16_t* __restrict__ xb, int N, int total4) {
    int i = blockIdx.x * blockDim.x + threadIdx.x;
    if (i >= total4) return;
    size_t base = (size_t)i * 4;
    size_t nx = (size_t)N * INF;
    const float* s = (base < nx) ? (x + base) : (emb + (base - nx));
    float4 v = *reinterpret_cast<const float4*>(s);
    bf16x4 o;
    o[0] = (__bf16)v.x; o[1] = (__bf16)v.y; o[2] = (__bf16)v.z; o[3] = (__bf16)v.w;
    *reinterpret_cast<bf16x4*>(xb + base) = o;
}

// in-degree for both directions. TD: d=dst side. BU: d=src side. Virtual edge N->root.
__global__ void k_degboth(const int* __restrict__ src, const int* __restrict__ dst,
                          const int* __restrict__ roots, int* __restrict__ indeg,
                          int E, int B, int N, int nv) {
    int e = blockIdx.x * blockDim.x + threadIdx.x;
    if (e >= E + B) return;
    int a, b;
    if (e < E) { a = src[e]; b = dst[e]; }
    else       { a = N;      b = roots[e - E]; }
    atomicAdd(&indeg[b], 1);        // TD
    atomicAdd(&indeg[nv + a], 1);   // BU
}

__global__ void k_dinvboth(const int* __restrict__ indeg, float* __restrict__ dinv, int n2) {
    int i = blockIdx.x * blockDim.x + threadIdx.x;
    if (i < n2) dinv[i] = rsqrtf(1.0f + (float)indeg[i]);  // +1 self-loop
}

#define SCAN_STRIDE 512

// per-256-chunk sums
__global__ __launch_bounds__(256) void k_scan1(const int* __restrict__ indeg, int* __restrict__ bsum, int nv) {
    int dir = blockIdx.y;
    __shared__ int s[256];
    int t = threadIdx.x;
    int v = blockIdx.x * 256 + t;
    s[t] = (v < nv) ? indeg[dir * nv + v] : 0;
    __syncthreads();
    for (int off = 128; off > 0; off >>= 1) {
        if (t < off) s[t] += s[t + off];
        __syncthreads();
    }
    if (t == 0) bsum[dir * SCAN_STRIDE + blockIdx.x] = s[0];
}

// exclusive scan of block sums (nblk <= 512)
__global__ __launch_bounds__(512) void k_scan2(int* __restrict__ bsum, int nblk) {
    int dir = blockIdx.y;
    int* p = bsum + dir * SCAN_STRIDE;
    __shared__ int s[512];
    int t = threadIdx.x;
    int v = (t < nblk) ? p[t] : 0;
    s[t] = v;
    __syncthreads();
    for (int off = 1; off < 512; off <<= 1) {
        int u = (t >= off) ? s[t - off] : 0;
        __syncthreads();
        s[t] += u;
        __syncthreads();
    }
    if (t < nblk) p[t] = s[t] - v;  // exclusive
}

// per-element exclusive offsets + cursor copy
__global__ __launch_bounds__(256) void k_scan3(const int* __restrict__ indeg, const int* __restrict__ bsum,
                                               int* __restrict__ off, int* __restrict__ cursor,
                                               int nv, int total) {
    int dir = blockIdx.y;
    __shared__ int s[256];
    int t = threadIdx.x;
    int v0 = blockIdx.x * 256 + t;
    int val = (v0 < nv) ? indeg[dir * nv + v0] : 0;
    s[t] = val;
    __syncthreads();
    for (int o = 1; o < 256; o <<= 1) {
        int u = (t >= o) ? s[t - o] : 0;
        __syncthreads();
        s[t] += u;
        __syncthreads();
    }
    int excl = s[t] - val + bsum[dir * SCAN_STRIDE + blockIdx.x];
    if (v0 < nv) {
        off[dir * (nv + 1) + v0] = excl;
        cursor[dir * nv + v0] = excl;
    }
    if (blockIdx.x == 0 && t == 0) off[dir * (nv + 1) + nv] = total;
}

// fill slot lists for both directions
__global__ void k_fill(const int* __restrict__ src, const int* __restrict__ dst,
                       const int* __restrict__ roots, int* __restrict__ cursor,
                       int* __restrict__ slots, int E, int B, int N, int nv) {
    int e = blockIdx.x * blockDim.x + threadIdx.x;
    if (e >= E + B) return;
    int a, b;
    if (e < E) { a = src[e]; b = dst[e]; }
    else       { a = N;      b = roots[e - E]; }
    int p = atomicAdd(&cursor[b], 1);            // TD: d=b, s=a
    slots[p] = a;
    p = atomicAdd(&cursor[nv + a], 1);           // BU: d=a, s=b
    slots[(E + B) + p] = b;
}

// MFMA GEMM: raws[r][c] = dinv[r] * sum_k A[r][k] * W[k][c]   (A bf16, prefetch-all)
template<int K>
__global__ __launch_bounds__(256) void k_gemm(
    const bf16_t* __restrict__ A, const bf16_t* __restrict__ Wf,
    const float* __restrict__ dinv, bf16_t* __restrict__ raws, int nv)
{
    constexpr int NK = K / 32;
    int lane = threadIdx.x & 63;
    int wave = threadIdx.x >> 6;
    int rowbase = blockIdx.x * 64 + wave * 16;
    int r = rowbase + (lane & 15);
    int rc = (r < nv) ? r : (nv - 1);   // clamp; out-of-range output rows never written
    int kseg = lane >> 4;

    const bf16_t* ar = A + (size_t)rc * K + kseg * 8;
    bf16x8 a[NK];
    #pragma unroll
    for (int kk = 0; kk < NK; ++kk)
        a[kk] = *reinterpret_cast<const bf16x8*>(ar + kk * 32);

    f32x4 acc[8] = {};
    #pragma unroll
    for (int kk = 0; kk < NK; ++kk) {
        #pragma unroll
        for (int n = 0; n < 8; ++n) {
            bf16x8 b = *reinterpret_cast<const bf16x8*>(Wf + (size_t)((((kk << 3) + n) << 6) + lane) * 8);
            acc[n] = __builtin_amdgcn_mfma_f32_16x16x32_bf16(a[kk], b, acc[n], 0, 0, 0);
        }
    }

    int ccol = lane & 15;
    int cg = lane >> 4;
    #pragma unroll
    for (int i = 0; i < 4; ++i) {
        int rr = rowbase + cg * 4 + i;
        if (rr >= nv) continue;
        float di = dinv[rr];
        bf16_t* orow = raws + (size_t)rr * HF + ccol;
        #pragma unroll
        for (int n = 0; n < 8; ++n)
            orow[n * 16] = (bf16_t)(acc[n][i] * di);
    }
}

// layer-1 gather: ab[v] = bf16(relu(dinv[v]*(raws[v] + sum_in raws[s]) + bias))
__global__ __launch_bounds__(128) void k_gather1(
    const bf16_t* __restrict__ raws, const int* __restrict__ off, const int* __restrict__ slots,
    const float* __restrict__ dinv, const float* __restrict__ bias,
    bf16_t* __restrict__ ab, int nv)
{
    int t = threadIdx.x;
    int v0 = blockIdx.x * 4;
    float bs = bias[t];
    #pragma unroll 1
    for (int k = 0; k < 4; ++k) {
        int v = v0 + k;
        if (v >= nv) break;
        float sum = (float)raws[(size_t)v * HF + t];
        int e0 = off[v], e1 = off[v + 1];
        for (int i = e0; i < e1; ++i) {
            int s = slots[i];
            sum += (float)raws[(size_t)s * HF + t];
        }
        float val = dinv[v] * sum + bs;
        ab[(size_t)v * HF + t] = (bf16_t)fmaxf(val, 0.f);
    }
}

// layer-2 gather fused with graph pooling. Virtual row -> vrow.
__global__ __launch_bounds__(128) void k_gather2pool(
    const bf16_t* __restrict__ raws, const int* __restrict__ off, const int* __restrict__ slots,
    const float* __restrict__ dinv, const float* __restrict__ bias, const int* __restrict__ batch,
    float* __restrict__ pooled, float* __restrict__ vrow, int nv, int N)
{
    int t = threadIdx.x;
    int v0 = blockIdx.x * 8;
    float bs = bias[t];
    float accum = 0.f;
    int curg = -1;
    #pragma unroll 1
    for (int k = 0; k < 8; ++k) {
        int v = v0 + k;
        if (v >= nv) break;
        float sum = (float)raws[(size_t)v * HF + t];
        int e0 = off[v], e1 = off[v + 1];
        for (int i = e0; i < e1; ++i)
            sum += (float)raws[(size_t)slots[i] * HF + t];
        float val = dinv[v] * sum + bs;
        if (v == N) { vrow[t] = val; continue; }
        int g = batch[v];
        if (g != curg) {
            if (curg >= 0) atomicAdd(&pooled[curg * HF + t], accum);
            curg = g; accum = 0.f;
        }
        accum += val;
    }
    if (curg >= 0) atomicAdd(&pooled[curg * HF + t], accum);
}

// out = relu([bu+vbu, td+vtd] @ w1 + b1) @ w2 + b2
__global__ __launch_bounds__(256) void k_mlp(const float* __restrict__ p_bu, const float* __restrict__ p_td,
                                             const float* __restrict__ vrow_bu, const float* __restrict__ vrow_td,
                                             const float* __restrict__ w1, const float* __restrict__ b1,
                                             const float* __restrict__ w2, const float* __restrict__ b2,
                                             float* __restrict__ out) {
    __shared__ float invec[256];
    __shared__ float hid[256];
    int g = blockIdx.x;
    int t = threadIdx.x;
    invec[t] = (t < 128) ? (p_bu[g * 128 + t] + vrow_bu[t])
                         : (p_td[g * 128 + (t - 128)] + vrow_td[t - 128]);
    __syncthreads();
    float acc = b1[t];
    #pragma unroll 8
    for (int k = 0; k < 256; ++k) acc = fmaf(invec[k], w1[k * 256 + t], acc);
    hid[t] = acc > 0.f ? acc : 0.f;
    __syncthreads();
    if (t < 128) {
        float o = b2[t];
        #pragma unroll 8
        for (int k = 0; k < 256; ++k) o = fmaf(hid[k], w2[k * 128 + t], o);
        out[g * 128 + t] = o;
    }
}

extern "C" void kernel_launch(void* const* d_in, const int* in_sizes, int n_in,
                              void* d_out, int out_size, void* d_ws, size_t ws_size,
                              hipStream_t stream) {
    const float* x     = (const float*)d_in[0];
    const float* emb_w = (const float*)d_in[1];
    const float* td_w1 = (const float*)d_in[2];
    const float* td_b1 = (const float*)d_in[3];
    const float* td_w2 = (const float*)d_in[4];
    const float* td_b2 = (const float*)d_in[5];
    const float* bu_w1 = (const float*)d_in[6];
    const float* bu_b1 = (const float*)d_in[7];
    const float* bu_w2 = (const float*)d_in[8];
    const float* bu_b2 = (const float*)d_in[9];
    const float* p_w1  = (const float*)d_in[10];
    const float* p_b1  = (const float*)d_in[11];
    const float* p_w2  = (const float*)d_in[12];
    const float* p_b2  = (const float*)d_in[13];
    const int*   ei    = (const int*)d_in[14];
    const int*   batch = (const int*)d_in[15];

    int N = in_sizes[0] / INF;
    int E = in_sizes[14] / 2;
    int B = out_size / 128;
    int nv = N + 1;
    int EB = E + B;
    const int* src = ei;
    const int* dst = ei + E;

    // ---- workspace carve-up ----
    char* wsp = (char*)d_ws;
    auto alloc = [&](size_t bytes) { char* p = wsp; wsp += (bytes + 255) & ~(size_t)255; return p; };
    // zero region: [indeg 2*nv][pooled 2*B*HF][vrow 2*HF]
    int zwords = 2 * nv + 2 * B * HF + 2 * HF;
    int*    Z      = (int*)   alloc((size_t)zwords * 4);
    int*    indeg  = Z;
    float*  pooled = (float*)(Z + 2 * nv);
    float*  vrow   = pooled + 2 * B * HF;
    float*  dinv   = (float*) alloc((size_t)2 * nv * 4);
    int*    off    = (int*)   alloc((size_t)2 * (nv + 1) * 4);
    int*    cursor = (int*)   alloc((size_t)2 * nv * 4);
    int*    slots  = (int*)   alloc((size_t)2 * EB * 4);
    int*    bsum   = (int*)   alloc((size_t)2 * SCAN_STRIDE * 4);
    int*    roots  = (int*)   alloc((size_t)(B + 1) * 4);
    bf16_t* Wf     = (bf16_t*)alloc((size_t)98304 * 2);
    bf16_t* XB     = (bf16_t*)alloc((size_t)nv * INF * 2);
    bf16_t* RAWS   = (bf16_t*)alloc((size_t)nv * HF * 2);
    bf16_t* AB     = (bf16_t*)alloc((size_t)nv * HF * 2);

    float* p_td = pooled;
    float* p_bu = pooled + (size_t)B * HF;
    float* vrow_td = vrow;
    float* vrow_bu = vrow + HF;
    float* out = (float*)d_out;

    dim3 b256(256), b128(128);
    int nblk = (nv + 255) / 256;

    k_roots<<<dim3((N + 255) / 256), b256, 0, stream>>>(batch, roots, N, B);
    k_zero<<<dim3((zwords + 255) / 256), b256, 0, stream>>>(Z, zwords);
    k_wswz4<<<dim3((98304 + 255) / 256), b256, 0, stream>>>(td_w1, td_w2, bu_w1, bu_w2, Wf);
    int total4 = nv * INF / 4;
    k_xcvt<<<dim3((total4 + 255) / 256), b256, 0, stream>>>(x, emb_w, XB, N, total4);
    k_degboth<<<dim3((EB + 255) / 256), b256, 0, stream>>>(src, dst, roots, indeg, E, B, N, nv);
    k_dinvboth<<<dim3((2 * nv + 255) / 256), b256, 0, stream>>>(indeg, dinv, 2 * nv);
    k_scan1<<<dim3(nblk, 2), b256, 0, stream>>>(indeg, bsum, nv);
    k_scan2<<<dim3(1, 2), dim3(512), 0, stream>>>(bsum, nblk);
    k_scan3<<<dim3(nblk, 2), b256, 0, stream>>>(indeg, bsum, off, cursor, nv, EB);
    k_fill<<<dim3((EB + 255) / 256), b256, 0, stream>>>(src, dst, roots, cursor, slots, E, B, N, nv);

    int nvb = (nv + 63) / 64;
    bf16_t* w1f_td = Wf;
    bf16_t* w2f_td = Wf + 32768;
    bf16_t* w1f_bu = Wf + 49152;
    bf16_t* w2f_bu = Wf + 81920;

    for (int dir = 0; dir < 2; ++dir) {  // 0 = TD, 1 = BU
        const bf16_t* w1f = dir ? w1f_bu : w1f_td;
        const float*  b1  = dir ? bu_b1 : td_b1;
        const bf16_t* w2f = dir ? w2f_bu : w2f_td;
        const float*  b2  = dir ? bu_b2 : td_b2;
        float* pb   = dir ? p_bu : p_td;
        float* vr   = dir ? vrow_bu : vrow_td;
        const float* dv  = dinv + (size_t)dir * nv;
        const int*   ofd = off + (size_t)dir * (nv + 1);
        const int*   sld = slots + (size_t)dir * EB;

        k_gemm<INF><<<dim3(nvb), b256, 0, stream>>>(XB, w1f, dv, RAWS, nv);
        k_gather1<<<dim3((nv + 3) / 4), b128, 0, stream>>>(RAWS, ofd, sld, dv, b1, AB, nv);
        k_gemm<HF><<<dim3(nvb), b256, 0, stream>>>(AB, w2f, dv, RAWS, nv);
        k_gather2pool<<<dim3((nv + 7) / 8), b128, 0, stream>>>(RAWS, ofd, sld, dv, b2, batch, pb, vr, nv, N);
    }

    k_mlp<<<dim3(B), b256, 0, stream>>>(p_bu, p_td, vrow_bu, vrow_td, p_w1, p_b1, p_w2, p_b2, out);
}

// Round 4
// 338.610 us; speedup vs baseline: 4.3500x; 1.0669x over previous
//
#include <hip/hip_runtime.h>

typedef __bf16 bf16_t;
typedef __bf16 bf16x8 __attribute__((ext_vector_type(8)));
typedef float f32x4 __attribute__((ext_vector_type(4)));

#define INF 256
#define HF 128
#define NPB 16
#define CH 8
#define SCAN_STRIDE 512

// ---- roots[g] = first node of graph g (batch sorted, all graphs non-empty) ----
__global__ void k_roots(const int* __restrict__ batch, int* __restrict__ roots, int N, int B) {
    int i = blockIdx.x * blockDim.x + threadIdx.x;
    if (i == 0) roots[B] = N;
    if (i < N) {
        if (i == 0) roots[batch[0]] = 0;
        else if (batch[i] != batch[i - 1]) roots[batch[i]] = i;
    }
}

__global__ void k_zero(int* __restrict__ p, int n) {
    int i = blockIdx.x * blockDim.x + threadIdx.x;
    if (i < n) p[i] = 0;
}

// two W1 matrices (256x128 f32) -> bf16 MFMA B-fragment order, 32768 each
__global__ void k_wswz2(const float* __restrict__ tw1, const float* __restrict__ bw1,
                        bf16_t* __restrict__ o) {
    int idx = blockIdx.x * blockDim.x + threadIdx.x;
    if (idx >= 65536) return;
    const float* W = (idx < 32768) ? tw1 : bw1;
    bf16_t* out = o + (idx & 32768);
    int i = idx & 32767;
    int j  = i & 7;
    int l  = (i >> 3) & 63;
    int t  = i >> 9;          // kk*8 + n
    int n  = t & 7;
    int kk = t >> 3;
    int k  = kk * 32 + ((l >> 4) << 3) + j;
    int c  = (n << 4) + (l & 15);
    out[i] = (bf16_t)W[k * HF + c];
}

// in-degree for both directions. TD: d=dst. BU: d=src. Virtual edge N->root.
__global__ void k_degboth(const int* __restrict__ src, const int* __restrict__ dst,
                          const int* __restrict__ roots, int* __restrict__ indeg,
                          int E, int B, int N, int nv) {
    int e = blockIdx.x * blockDim.x + threadIdx.x;
    if (e >= E + B) return;
    int a, b;
    if (e < E) { a = src[e]; b = dst[e]; }
    else       { a = N;      b = roots[e - E]; }
    atomicAdd(&indeg[b], 1);        // TD
    atomicAdd(&indeg[nv + a], 1);   // BU
}

__global__ void k_dinvboth(const int* __restrict__ indeg, float* __restrict__ dinv, int n2) {
    int i = blockIdx.x * blockDim.x + threadIdx.x;
    if (i < n2) dinv[i] = rsqrtf(1.0f + (float)indeg[i]);  // +1 self-loop
}

// per-256-chunk sums
__global__ __launch_bounds__(256) void k_scan1(const int* __restrict__ indeg, int* __restrict__ bsum, int nv) {
    int dir = blockIdx.y;
    __shared__ int s[256];
    int t = threadIdx.x;
    int v = blockIdx.x * 256 + t;
    s[t] = (v < nv) ? indeg[dir * nv + v] : 0;
    __syncthreads();
    for (int off = 128; off > 0; off >>= 1) {
        if (t < off) s[t] += s[t + off];
        __syncthreads();
    }
    if (t == 0) bsum[dir * SCAN_STRIDE + blockIdx.x] = s[0];
}

// exclusive scan of block sums (nblk <= 512)
__global__ __launch_bounds__(512) void k_scan2(int* __restrict__ bsum, int nblk) {
    int dir = blockIdx.y;
    int* p = bsum + dir * SCAN_STRIDE;
    __shared__ int s[512];
    int t = threadIdx.x;
    int v = (t < nblk) ? p[t] : 0;
    s[t] = v;
    __syncthreads();
    for (int off = 1; off < 512; off <<= 1) {
        int u = (t >= off) ? s[t - off] : 0;
        __syncthreads();
        s[t] += u;
        __syncthreads();
    }
    if (t < nblk) p[t] = s[t] - v;  // exclusive
}

// per-element exclusive offsets + cursor copy
__global__ __launch_bounds__(256) void k_scan3(const int* __restrict__ indeg, const int* __restrict__ bsum,
                                               int* __restrict__ off, int* __restrict__ cursor,
                                               int nv, int total) {
    int dir = blockIdx.y;
    __shared__ int s[256];
    int t = threadIdx.x;
    int v0 = blockIdx.x * 256 + t;
    int val = (v0 < nv) ? indeg[dir * nv + v0] : 0;
    s[t] = val;
    __syncthreads();
    for (int o = 1; o < 256; o <<= 1) {
        int u = (t >= o) ? s[t - o] : 0;
        __syncthreads();
        s[t] += u;
        __syncthreads();
    }
    int excl = s[t] - val + bsum[dir * SCAN_STRIDE + blockIdx.x];
    if (v0 < nv) {
        off[dir * (nv + 1) + v0] = excl;
        cursor[dir * nv + v0] = excl;
    }
    if (blockIdx.x == 0 && t == 0) off[dir * (nv + 1) + nv] = total;
}

// fill slot lists for both directions
__global__ void k_fill(const int* __restrict__ src, const int* __restrict__ dst,
                       const int* __restrict__ roots, int* __restrict__ cursor,
                       int* __restrict__ slots, int E, int B, int N, int nv) {
    int e = blockIdx.x * blockDim.x + threadIdx.x;
    if (e >= E + B) return;
    int a, b;
    if (e < E) { a = src[e]; b = dst[e]; }
    else       { a = N;      b = roots[e - E]; }
    int p = atomicAdd(&cursor[b], 1);            // TD: d=b, s=a
    slots[p] = a;
    p = atomicAdd(&cursor[nv + a], 1);           // BU: d=a, s=b
    slots[(E + B) + p] = b;
}

// Dual-direction MFMA GEMM1 reading f32 X directly:
//   rawsTD[r] = dinvTD[r]*(X W1td)[r], rawsBU[r] = dinvBU[r]*(X W1bu)[r]  (bf16)
__global__ __launch_bounds__(256) void k_gemm1both(
    const float* __restrict__ x, const float* __restrict__ emb,
    const bf16_t* __restrict__ WfTD, const bf16_t* __restrict__ WfBU,
    const float* __restrict__ dinvTD, const float* __restrict__ dinvBU,
    bf16_t* __restrict__ rawsTD, bf16_t* __restrict__ rawsBU,
    int nv, int N)
{
    int lane = threadIdx.x & 63;
    int wave = threadIdx.x >> 6;
    int rowbase = blockIdx.x * 64 + wave * 16;
    int r = rowbase + (lane & 15);
    int kseg = lane >> 4;
    const float* xr = (r < N) ? (x + (size_t)r * INF) : emb;

    bf16x8 a[8];
    // two half-phases: 8 float4 loads in flight each
    #pragma unroll
    for (int h = 0; h < 2; ++h) {
        float4 f[8];
        #pragma unroll
        for (int kk = 0; kk < 4; ++kk) {
            int k0 = (h * 4 + kk) * 32 + kseg * 8;
            f[2 * kk]     = *reinterpret_cast<const float4*>(xr + k0);
            f[2 * kk + 1] = *reinterpret_cast<const float4*>(xr + k0 + 4);
        }
        #pragma unroll
        for (int kk = 0; kk < 4; ++kk) {
            bf16x8 av;
            av[0] = (__bf16)f[2 * kk].x;     av[1] = (__bf16)f[2 * kk].y;
            av[2] = (__bf16)f[2 * kk].z;     av[3] = (__bf16)f[2 * kk].w;
            av[4] = (__bf16)f[2 * kk + 1].x; av[5] = (__bf16)f[2 * kk + 1].y;
            av[6] = (__bf16)f[2 * kk + 1].z; av[7] = (__bf16)f[2 * kk + 1].w;
            a[h * 4 + kk] = av;
        }
    }

    f32x4 accT[8] = {}, accB[8] = {};
    #pragma unroll
    for (int kk = 0; kk < 8; ++kk) {
        #pragma unroll
        for (int n = 0; n < 8; ++n) {
            size_t wi = (size_t)((((kk << 3) + n) << 6) + lane) * 8;
            bf16x8 bt = *reinterpret_cast<const bf16x8*>(WfTD + wi);
            accT[n] = __builtin_amdgcn_mfma_f32_16x16x32_bf16(a[kk], bt, accT[n], 0, 0, 0);
            bf16x8 bb = *reinterpret_cast<const bf16x8*>(WfBU + wi);
            accB[n] = __builtin_amdgcn_mfma_f32_16x16x32_bf16(a[kk], bb, accB[n], 0, 0, 0);
        }
    }

    int ccol = lane & 15;
    int cg = lane >> 4;
    #pragma unroll
    for (int i = 0; i < 4; ++i) {
        int rr = rowbase + cg * 4 + i;
        if (rr >= nv) continue;
        float diT = dinvTD[rr], diB = dinvBU[rr];
        bf16_t* oT = rawsTD + (size_t)rr * HF + ccol;
        bf16_t* oB = rawsBU + (size_t)rr * HF + ccol;
        #pragma unroll
        for (int n = 0; n < 8; ++n) {
            oT[n * 16] = (bf16_t)(accT[n][i] * diT);
            oB[n * 16] = (bf16_t)(accB[n][i] * diB);
        }
    }
}

// layer-1 gather, both dirs: ab[v] = relu(dinv[v]*(raws[v] + sum_in raws[s]) + b1)
__global__ __launch_bounds__(128) void k_gather1(
    const bf16_t* __restrict__ raws, const int* __restrict__ off, const int* __restrict__ slots,
    const float* __restrict__ dinv,
    const float* __restrict__ td_b1, const float* __restrict__ bu_b1,
    bf16_t* __restrict__ ab, int nv, int EB)
{
    int dir = blockIdx.y;
    const bf16_t* R  = raws + (size_t)dir * nv * HF;
    const int*    OF = off + (size_t)dir * (nv + 1);
    const int*    SL = slots + (size_t)dir * EB;
    const float*  DV = dinv + (size_t)dir * nv;
    const float*  bias = dir ? bu_b1 : td_b1;
    bf16_t* AB = ab + (size_t)dir * nv * HF;

    __shared__ float lsum[NPB][HF];
    int t = threadIdx.x;
    int v0 = blockIdx.x * NPB;
    int nloc = min(NPB, nv - v0);

    int roff[NPB + 1];
    #pragma unroll
    for (int j = 0; j <= NPB; ++j)
        roff[j] = OF[min(v0 + j, nv)];

    #pragma unroll 1
    for (int j = 0; j < nloc; ++j)
        lsum[j][t] = (float)R[(size_t)(v0 + j) * HF + t];

    int e1 = roff[NPB];
    #pragma unroll 1
    for (int i = roff[0]; i < e1; i += CH) {
        int cnt = min(CH, e1 - i);
        int sl[CH]; float vals[CH];
        #pragma unroll
        for (int u = 0; u < CH; ++u) if (u < cnt) sl[u] = SL[i + u];
        #pragma unroll
        for (int u = 0; u < CH; ++u) if (u < cnt) vals[u] = (float)R[(size_t)sl[u] * HF + t];
        #pragma unroll
        for (int u = 0; u < CH; ++u) if (u < cnt) {
            int e = i + u, j = 0;
            #pragma unroll
            for (int j2 = 1; j2 < NPB; ++j2) j += (e >= roff[j2]) ? 1 : 0;
            lsum[j][t] += vals[u];
        }
    }

    float bs = bias[t];
    #pragma unroll 1
    for (int j = 0; j < nloc; ++j) {
        int v = v0 + j;
        float val = DV[v] * lsum[j][t] + bs;
        AB[(size_t)v * HF + t] = (bf16_t)fmaxf(val, 0.f);
    }
}

// layer-2 gather on H (pre-W2), fused with graph pooling of (A_hat H):
//   G[v] = dinv[v]*(dinv[v]*H[v] + sum_in dinv[s]*H[s]); pooled_pre[g] += G[v]; vrow_pre = G[N]
__global__ __launch_bounds__(128) void k_gather2pool(
    const bf16_t* __restrict__ ab, const int* __restrict__ off, const int* __restrict__ slots,
    const float* __restrict__ dinv, const int* __restrict__ batch,
    float* __restrict__ pooled, float* __restrict__ vrow,
    int nv, int EB, int N, int B)
{
    int dir = blockIdx.y;
    const bf16_t* A  = ab + (size_t)dir * nv * HF;
    const int*    OF = off + (size_t)dir * (nv + 1);
    const int*    SL = slots + (size_t)dir * EB;
    const float*  DV = dinv + (size_t)dir * nv;
    float* PP = pooled + (size_t)dir * B * HF;
    float* VR = vrow + dir * HF;

    __shared__ float lsum[NPB][HF];
    int t = threadIdx.x;
    int v0 = blockIdx.x * NPB;
    int nloc = min(NPB, nv - v0);

    int roff[NPB + 1];
    #pragma unroll
    for (int j = 0; j <= NPB; ++j)
        roff[j] = OF[min(v0 + j, nv)];

    #pragma unroll 1
    for (int j = 0; j < nloc; ++j) {
        int v = v0 + j;
        lsum[j][t] = DV[v] * (float)A[(size_t)v * HF + t];
    }

    int e1 = roff[NPB];
    #pragma unroll 1
    for (int i = roff[0]; i < e1; i += CH) {
        int cnt = min(CH, e1 - i);
        int sl[CH]; float vals[CH]; float dsv[CH];
        #pragma unroll
        for (int u = 0; u < CH; ++u) if (u < cnt) sl[u] = SL[i + u];
        #pragma unroll
        for (int u = 0; u < CH; ++u) if (u < cnt) {
            dsv[u] = DV[sl[u]];
            vals[u] = (float)A[(size_t)sl[u] * HF + t];
        }
        #pragma unroll
        for (int u = 0; u < CH; ++u) if (u < cnt) {
            int e = i + u, j = 0;
            #pragma unroll
            for (int j2 = 1; j2 < NPB; ++j2) j += (e >= roff[j2]) ? 1 : 0;
            lsum[j][t] += dsv[u] * vals[u];
        }
    }

    float accum = 0.f;
    int curg = -1;
    #pragma unroll 1
    for (int j = 0; j < nloc; ++j) {
        int v = v0 + j;
        float G = DV[v] * lsum[j][t];
        if (v == N) { VR[t] = G; continue; }
        int g = batch[v];
        if (g != curg) {
            if (curg >= 0) atomicAdd(&PP[curg * HF + t], accum);
            curg = g; accum = 0.f;
        }
        accum += G;
    }
    if (curg >= 0) atomicAdd(&PP[curg * HF + t], accum);
}

// Per graph: z = pooled_pre + vrow_pre; u = z @ W2 + (cnt+1)*b2 per branch;
// out = relu([u_bu, u_td] @ w1 + b1) @ w2 + b2
__global__ __launch_bounds__(256) void k_mlp(
    const float* __restrict__ pooled, const float* __restrict__ vrow, const int* __restrict__ roots,
    const float* __restrict__ td_w2, const float* __restrict__ td_b2,
    const float* __restrict__ bu_w2, const float* __restrict__ bu_b2,
    const float* __restrict__ w1, const float* __restrict__ b1,
    const float* __restrict__ w2, const float* __restrict__ b2,
    float* __restrict__ out, int B)
{
    __shared__ float zsh[256];
    __shared__ float invec[256];
    __shared__ float hid[256];
    int g = blockIdx.x;
    int t = threadIdx.x;
    const float* pp_td = pooled;
    const float* pp_bu = pooled + (size_t)B * HF;
    const float* vr_td = vrow;
    const float* vr_bu = vrow + HF;
    // zsh[0:128] = bu, zsh[128:256] = td
    zsh[t] = (t < 128) ? (pp_bu[g * HF + t] + vr_bu[t])
                       : (pp_td[g * HF + (t - 128)] + vr_td[t - 128]);
    __syncthreads();
    float cnt1 = (float)(roots[g + 1] - roots[g] + 1);
    float acc2;
    if (t < 128) {
        acc2 = cnt1 * bu_b2[t];
        #pragma unroll 8
        for (int k = 0; k < 128; ++k) acc2 = fmaf(zsh[k], bu_w2[k * HF + t], acc2);
    } else {
        int tt = t - 128;
        acc2 = cnt1 * td_b2[tt];
        #pragma unroll 8
        for (int k = 0; k < 128; ++k) acc2 = fmaf(zsh[128 + k], td_w2[k * HF + tt], acc2);
    }
    invec[t] = acc2;
    __syncthreads();
    float acc = b1[t];
    #pragma unroll 8
    for (int k = 0; k < 256; ++k) acc = fmaf(invec[k], w1[k * 256 + t], acc);
    hid[t] = acc > 0.f ? acc : 0.f;
    __syncthreads();
    if (t < 128) {
        float o = b2[t];
        #pragma unroll 8
        for (int k = 0; k < 256; ++k) o = fmaf(hid[k], w2[k * 128 + t], o);
        out[g * 128 + t] = o;
    }
}

extern "C" void kernel_launch(void* const* d_in, const int* in_sizes, int n_in,
                              void* d_out, int out_size, void* d_ws, size_t ws_size,
                              hipStream_t stream) {
    const float* x     = (const float*)d_in[0];
    const float* emb_w = (const float*)d_in[1];
    const float* td_w1 = (const float*)d_in[2];
    const float* td_b1 = (const float*)d_in[3];
    const float* td_w2 = (const float*)d_in[4];
    const float* td_b2 = (const float*)d_in[5];
    const float* bu_w1 = (const float*)d_in[6];
    const float* bu_b1 = (const float*)d_in[7];
    const float* bu_w2 = (const float*)d_in[8];
    const float* bu_b2 = (const float*)d_in[9];
    const float* p_w1  = (const float*)d_in[10];
    const float* p_b1  = (const float*)d_in[11];
    const float* p_w2  = (const float*)d_in[12];
    const float* p_b2  = (const float*)d_in[13];
    const int*   ei    = (const int*)d_in[14];
    const int*   batch = (const int*)d_in[15];

    int N = in_sizes[0] / INF;
    int E = in_sizes[14] / 2;
    int B = out_size / 128;
    int nv = N + 1;
    int EB = E + B;
    const int* src = ei;
    const int* dst = ei + E;

    // ---- workspace carve-up ----
    char* wsp = (char*)d_ws;
    auto alloc = [&](size_t bytes) { char* p = wsp; wsp += (bytes + 255) & ~(size_t)255; return p; };
    // zero region: [indeg 2*nv][pooled 2*B*HF][vrow 2*HF]
    int zwords = 2 * nv + 2 * B * HF + 2 * HF;
    int*    Z      = (int*)   alloc((size_t)zwords * 4);
    int*    indeg  = Z;
    float*  pooled = (float*)(Z + 2 * nv);
    float*  vrow   = pooled + 2 * B * HF;
    float*  dinv   = (float*) alloc((size_t)2 * nv * 4);
    int*    off    = (int*)   alloc((size_t)2 * (nv + 1) * 4);
    int*    cursor = (int*)   alloc((size_t)2 * nv * 4);
    int*    slots  = (int*)   alloc((size_t)2 * EB * 4);
    int*    bsum   = (int*)   alloc((size_t)2 * SCAN_STRIDE * 4);
    int*    roots  = (int*)   alloc((size_t)(B + 1) * 4);
    bf16_t* Wf     = (bf16_t*)alloc((size_t)65536 * 2);
    bf16_t* RAWS   = (bf16_t*)alloc((size_t)2 * nv * HF * 2);  // dir-major
    bf16_t* AB     = (bf16_t*)alloc((size_t)2 * nv * HF * 2);  // dir-major

    float* out = (float*)d_out;

    dim3 b256(256), b128(128);
    int nblk = (nv + 255) / 256;
    int ngb = (nv + NPB - 1) / NPB;
    int nvb = (nv + 63) / 64;

    k_roots<<<dim3((N + 255) / 256), b256, 0, stream>>>(batch, roots, N, B);
    k_zero<<<dim3((zwords + 255) / 256), b256, 0, stream>>>(Z, zwords);
    k_wswz2<<<dim3((65536 + 255) / 256), b256, 0, stream>>>(td_w1, bu_w1, Wf);
    k_degboth<<<dim3((EB + 255) / 256), b256, 0, stream>>>(src, dst, roots, indeg, E, B, N, nv);
    k_dinvboth<<<dim3((2 * nv + 255) / 256), b256, 0, stream>>>(indeg, dinv, 2 * nv);
    k_scan1<<<dim3(nblk, 2), b256, 0, stream>>>(indeg, bsum, nv);
    k_scan2<<<dim3(1, 2), dim3(512), 0, stream>>>(bsum, nblk);
    k_scan3<<<dim3(nblk, 2), b256, 0, stream>>>(indeg, bsum, off, cursor, nv, EB);
    k_fill<<<dim3((EB + 255) / 256), b256, 0, stream>>>(src, dst, roots, cursor, slots, E, B, N, nv);

    k_gemm1both<<<dim3(nvb), b256, 0, stream>>>(
        x, emb_w, Wf, Wf + 32768, dinv, dinv + nv,
        RAWS, RAWS + (size_t)nv * HF, nv, N);

    k_gather1<<<dim3(ngb, 2), b128, 0, stream>>>(
        RAWS, off, slots, dinv, td_b1, bu_b1, AB, nv, EB);

    k_gather2pool<<<dim3(ngb, 2), b128, 0, stream>>>(
        AB, off, slots, dinv, batch, pooled, vrow, nv, EB, N, B);

    k_mlp<<<dim3(B), b256, 0, stream>>>(
        pooled, vrow, roots, td_w2, td_b2, bu_w2, bu_b2,
        p_w1, p_b1, p_w2, p_b2, out, B);
}